// Round 6
// baseline (421.460 us; speedup 1.0000x reference)
//
#include <hip/hip_runtime.h>
#include <cstdint>
#include <cstddef>

#define NHEAD 4
#define HID 64
#define NCOL 256          // NHEAD*HID
#define INDIM 128
#define PREDDIM 16
#define RELNUM 50
#define NLAYER 3
#define ECHUNK 8192       // edges per block in bucket build
#define DSHIFT 7          // 128 dsts per bucket
#define DPB 128           // dsts per bucket
#define MAXBUCK 1024      // >= ceil(N/DPB); LDS hist size
#define MLP_NODES 64      // nodes per block in MFMA MLP

typedef _Float16 half8 __attribute__((ext_vector_type(8)));
typedef float float4v __attribute__((ext_vector_type(4)));

// ---------------- W1 hi/lo f16 split (once) ----------------
// fp32 = hi + lo/2048 exactly to ~2^-22 rel; lo scaled x2048 so W~0.05
// residuals stay in f16 normal range (avoids denorm-flush error).
__global__ void split_w1(const float* __restrict__ W1,
                         _Float16* __restrict__ Wh, _Float16* __restrict__ Wl)
{
    int i = blockIdx.x * 256 + threadIdx.x;    // NCOL*INDIM = 32768 total
    float v = W1[i];
    _Float16 h = (_Float16)v;
    Wh[i] = h;
    Wl[i] = (_Float16)((v - (float)h) * 2048.0f);
}

// ---------------- node scoring MLP via split-f16 MFMA ----------------
// h0[n,head] = b2 + sum_c_in_head relu(dot(X[n,:],W1[c,:]) + b1[c]) * W2[c]
// Round-5: LDS-tiled fp32 GEMM was LDS-issue-bound (VALUBusy 50%, 3 b128
// reads per 32 FMA). Move the GEMM to the matrix pipe with hi/lo f16 split:
// C = Ah*Bh + (Ah*Bl' + Al'*Bh) * 2^-11  (lo pre-scaled x2048).
// Block = 64 nodes, wave w = 16-node m-tile. A-frags staged in LDS in exact
// fragment order (slot = lane ^ 2*ks: frag reads lane*16B conflict-free,
// staging writes spread uniformly). B-frags straight from L2 (Wh/Wl 128 KB).
__global__ __launch_bounds__(256, 1) void mlp_mfma_kernel(
    const float* __restrict__ X, const _Float16* __restrict__ Wh,
    const _Float16* __restrict__ Wl, const float* __restrict__ b1,
    const float* __restrict__ W2, const float* __restrict__ b2,
    float* __restrict__ h0, int N)
{
    // [mt][ks][slot][j] : A-fragment order, 16 KB each
    __shared__ _Float16 hA[4][4][64][8];
    __shared__ _Float16 lA[4][4][64][8];

    const int tid = threadIdx.x;
    const int n0  = blockIdx.x * MLP_NODES;

    // ---- stage X tile as hi/lo A-fragments ----
    #pragma unroll
    for (int r = 0; r < 4; r++) {
        int t    = r * 256 + tid;          // 0..1023 = 64 nodes x 16 j-groups
        int node = t >> 4;
        int jg   = t & 15;                 // k0 = jg*8
        int gn   = min(n0 + node, N - 1);  // clamp; stores guarded
        const float4* Xp = reinterpret_cast<const float4*>(X + (size_t)gn * INDIM + jg * 8);
        float4 x0 = Xp[0], x1 = Xp[1];
        float xs[8] = { x0.x,x0.y,x0.z,x0.w, x1.x,x1.y,x1.z,x1.w };
        half8 hv, lv;
        #pragma unroll
        for (int j = 0; j < 8; j++) {
            _Float16 hh = (_Float16)xs[j];
            hv[j] = hh;
            lv[j] = (_Float16)((xs[j] - (float)hh) * 2048.0f);
        }
        int ks = jg >> 2, q = jg & 3, mt = node >> 4, m = node & 15;
        int slot = (q * 16 + m) ^ (2 * ks);       // bank-spread swizzle
        *reinterpret_cast<half8*>(&hA[mt][ks][slot][0]) = hv;
        *reinterpret_cast<half8*>(&lA[mt][ks][slot][0]) = lv;
    }
    __syncthreads();

    const int w    = tid >> 6;             // wave = m-tile
    const int lane = tid & 63;
    const int n16  = lane & 15;            // col within 16-tile
    const int q    = lane >> 4;

    float4v acc[16], accs[16];
    #pragma unroll
    for (int ct = 0; ct < 16; ct++) {
        acc[ct]  = (float4v){0.f, 0.f, 0.f, 0.f};
        accs[ct] = (float4v){0.f, 0.f, 0.f, 0.f};
    }

    #pragma unroll
    for (int ks = 0; ks < 4; ks++) {
        int slot = lane ^ (2 * ks);
        half8 ah = *reinterpret_cast<const half8*>(&hA[w][ks][slot][0]);
        half8 al = *reinterpret_cast<const half8*>(&lA[w][ks][slot][0]);
        #pragma unroll
        for (int ct = 0; ct < 16; ct++) {
            int c = ct * 16 + n16;
            const _Float16* pb = Wh + c * INDIM + ks * 32 + q * 8;
            const _Float16* pl = Wl + c * INDIM + ks * 32 + q * 8;
            half8 bh = *reinterpret_cast<const half8*>(pb);
            half8 bl = *reinterpret_cast<const half8*>(pl);
            acc[ct]  = __builtin_amdgcn_mfma_f32_16x16x32_f16(ah, bh, acc[ct], 0, 0, 0);
            accs[ct] = __builtin_amdgcn_mfma_f32_16x16x32_f16(ah, bl, accs[ct], 0, 0, 0);
            accs[ct] = __builtin_amdgcn_mfma_f32_16x16x32_f16(al, bh, accs[ct], 0, 0, 0);
        }
    }

    // ---- epilogue: bias + relu + W2, per-head partials, width-16 reduce ----
    float s[4][4];   // [head][reg]
    #pragma unroll
    for (int h = 0; h < 4; h++)
        #pragma unroll
        for (int r = 0; r < 4; r++) s[h][r] = 0.f;

    #pragma unroll
    for (int ct = 0; ct < 16; ct++) {
        int c = ct * 16 + n16;             // head = ct>>2 (n16 < 16)
        float b1v = b1[c], w2v = W2[c];
        int h = ct >> 2;
        #pragma unroll
        for (int r = 0; r < 4; r++) {
            float v = acc[ct][r] + accs[ct][r] * (1.0f / 2048.0f);
            s[h][r] += fmaxf(v + b1v, 0.f) * w2v;
        }
    }
    #pragma unroll
    for (int h = 0; h < 4; h++)
        #pragma unroll
        for (int r = 0; r < 4; r++) {
            float v = s[h][r];
            v += __shfl_down(v, 8, 16);
            v += __shfl_down(v, 4, 16);
            v += __shfl_down(v, 2, 16);
            v += __shfl_down(v, 1, 16);
            s[h][r] = v;
        }
    if (n16 == 0) {
        #pragma unroll
        for (int r = 0; r < 4; r++) {
            int node = n0 + w * 16 + q * 4 + r;     // D row = q*4+reg
            if (node < N) {
                #pragma unroll
                for (int h = 0; h < 4; h++)
                    h0[(size_t)node * NHEAD + h] = s[h][r] + b2[h];
            }
        }
    }
}

// ---------------- attention weight table ----------------
__global__ void table_kernel(const float* __restrict__ rel_emb,
                             const float* __restrict__ W_pred,
                             float* __restrict__ wtab)
{
    int idx = blockIdx.x * blockDim.x + threadIdx.x;
    if (idx >= NLAYER * RELNUM * NHEAD) return;
    int h = idx & 3;
    int q = idx >> 2;
    int t = q % RELNUM;
    int l = q / RELNUM;
    float acc = 0.f;
    #pragma unroll
    for (int p = 0; p < PREDDIM; p++)
        acc = fmaf(rel_emb[t * PREDDIM + p], W_pred[l * PREDDIM * NHEAD + p * NHEAD + h], acc);
    float e = (acc >= 0.f) ? acc : 0.2f * acc;
    wtab[idx] = __expf(e);
}

// ---------------- bucketed CSR build ----------------
__global__ __launch_bounds__(256) void bucket_count_kernel(
    const int* __restrict__ dst, int* __restrict__ bucket_size, int E, int nbuck)
{
    __shared__ int hist[MAXBUCK];
    const int tid = threadIdx.x;
    #pragma unroll
    for (int r = 0; r < MAXBUCK / 256; r++) hist[r * 256 + tid] = 0;
    __syncthreads();
    const int base = blockIdx.x * ECHUNK;
    const int end  = min(base + ECHUNK, E);
    for (int i = base + tid; i < end; i += 256)
        atomicAdd(&hist[dst[i] >> DSHIFT], 1);
    __syncthreads();
    for (int b = tid; b < nbuck; b += 256)
        if (hist[b]) atomicAdd(&bucket_size[b], hist[b]);
}

__global__ __launch_bounds__(1024) void scan_buckets_kernel(
    const int* __restrict__ bucket_size, int* __restrict__ bucket_start,
    int* __restrict__ bucket_cursor, int nbuck)
{
    __shared__ int s[1024];
    const int t = threadIdx.x;
    int v = (t < nbuck) ? bucket_size[t] : 0;
    s[t] = v;
    __syncthreads();
    for (int off = 1; off < 1024; off <<= 1) {
        int u = (t >= off) ? s[t - off] : 0;
        __syncthreads();
        s[t] += u;
        __syncthreads();
    }
    if (t < nbuck) {
        int ex = s[t] - v;
        bucket_start[t]  = ex;
        bucket_cursor[t] = ex;
    }
}

__global__ __launch_bounds__(256) void bucket_scatter_kernel(
    const int* __restrict__ src, const int* __restrict__ dst,
    const int* __restrict__ types, int* __restrict__ bucket_cursor,
    int* __restrict__ bucketed, int E, int nbuck)
{
    __shared__ int hist[MAXBUCK];   // then per-bucket base
    __shared__ int cur[MAXBUCK];
    const int tid = threadIdx.x;
    #pragma unroll
    for (int r = 0; r < MAXBUCK / 256; r++) {
        hist[r * 256 + tid] = 0;
        cur[r * 256 + tid] = 0;
    }
    __syncthreads();
    const int base = blockIdx.x * ECHUNK;
    const int end  = min(base + ECHUNK, E);
    for (int i = base + tid; i < end; i += 256)
        atomicAdd(&hist[dst[i] >> DSHIFT], 1);
    __syncthreads();
    for (int b = tid; b < nbuck; b += 256) {
        int c = hist[b];
        if (c) hist[b] = atomicAdd(&bucket_cursor[b], c);   // reserve block's range
    }
    __syncthreads();
    for (int i = base + tid; i < end; i += 256) {
        int d = dst[i];
        int b = d >> DSHIFT;
        int r = atomicAdd(&cur[b], 1);
        bucketed[hist[b] + r] = src[i] | (types[i] << 17) | ((d & (DPB - 1)) << 23);
    }
}

__global__ __launch_bounds__(256) void bucket_to_csr_kernel(
    const int* __restrict__ bucket_start, const int* __restrict__ bucket_size,
    const int* __restrict__ bucketed, int* __restrict__ sorted,
    int* __restrict__ row_start, int* __restrict__ deg, int N)
{
    __shared__ int cnt[DPB];
    __shared__ int sc[DPB];
    __shared__ int rs[DPB];
    __shared__ int cur[DPB];
    const int tid = threadIdx.x;
    const int b   = blockIdx.x;
    const int d0  = b << DSHIFT;
    const int nd  = min(DPB, N - d0);
    const int s0  = bucket_start[b];
    const int ne  = bucket_size[b];

    if (tid < DPB) { cnt[tid] = 0; cur[tid] = 0; }
    __syncthreads();
    for (int i = tid; i < ne; i += 256)
        atomicAdd(&cnt[(bucketed[s0 + i] >> 23) & (DPB - 1)], 1);
    __syncthreads();
    int v = (tid < DPB) ? cnt[tid] : 0;
    if (tid < DPB) sc[tid] = v;
    __syncthreads();
    for (int off = 1; off < DPB; off <<= 1) {
        int u = (tid < DPB && tid >= off) ? sc[tid - off] : 0;
        __syncthreads();
        if (tid < DPB) sc[tid] += u;
        __syncthreads();
    }
    if (tid < DPB) {
        int ex = sc[tid] - v;
        rs[tid] = s0 + ex;
        if (tid < nd) {
            row_start[d0 + tid] = s0 + ex;
            deg[d0 + tid] = v;
        }
    }
    __syncthreads();
    for (int i = tid; i < ne; i += 256) {
        int pk = bucketed[s0 + i];
        int d  = (pk >> 23) & (DPB - 1);
        int r  = atomicAdd(&cur[d], 1);
        sorted[rs[d] + r] = pk & 0x7FFFFF;   // src | type<<17
    }
}

// ---------------- per-layer aggregation ----------------
template <int MODE>
__global__ __launch_bounds__(256) void agg_kernel(
    const int* __restrict__ row_start, const int* __restrict__ deg,
    const int* __restrict__ sorted, const float* __restrict__ wt_l,
    const float* __restrict__ hin, float* __restrict__ hout,
    const float* __restrict__ centrality, const float* __restrict__ gamma,
    const float* __restrict__ beta, int N)
{
    __shared__ float wt[RELNUM * NHEAD];
    for (int i = threadIdx.x; i < RELNUM * NHEAD; i += blockDim.x) wt[i] = wt_l[i];
    __syncthreads();

    int gid = blockIdx.x * blockDim.x + threadIdx.x;
    int d = gid >> 2, h = gid & 3;
    if (d >= N) return;

    int b = row_start[d], n = deg[d];
    float num = 0.f, den = 0.f;
    for (int i = 0; i < n; i++) {
        int pk = sorted[b + i];                 // same addr across the quad
        int s = pk & 0x1FFFF;
        int t = pk >> 17;
        float wv = wt[t * NHEAD + h];
        float hv = (MODE == 0) ? hin[(size_t)s * NHEAD + h] : hin[s];
        num = fmaf(wv, hv, num);
        den += wv;
    }
    float r = (n > 0) ? fmaxf(num / den, 0.f) : 0.f;   // relu(segsum(a*h))
    if (MODE == 2) r = (centrality[d] * gamma[h] + beta[h]) * r;
    r += __shfl_xor(r, 1);
    r += __shfl_xor(r, 2);
    r *= 0.25f;
    if (h == 0) {
        if (MODE < 2) hout[d] = r;
        else          hout[d] = (r > 0.f) ? r : 0.01f * r;
    }
}

// ---------------- launch ----------------
extern "C" void kernel_launch(void* const* d_in, const int* in_sizes, int n_in,
                              void* d_out, int out_size, void* d_ws, size_t ws_size,
                              hipStream_t stream)
{
    const float* X          = (const float*)d_in[0];
    const float* centrality = (const float*)d_in[1];
    const float* W1         = (const float*)d_in[2];
    const float* b1         = (const float*)d_in[3];
    const float* W2         = (const float*)d_in[4];
    const float* b2         = (const float*)d_in[5];
    const float* rel_emb    = (const float*)d_in[6];
    const float* W_pred     = (const float*)d_in[7];
    const float* gamma      = (const float*)d_in[8];
    const float* beta       = (const float*)d_in[9];
    const int*   edge_types = (const int*)d_in[10];
    const int*   src        = (const int*)d_in[11];
    const int*   dst        = (const int*)d_in[12];
    float* out = (float*)d_out;

    const int N = in_sizes[1];
    const int E = in_sizes[10];
    const int nbuck = (N + DPB - 1) / DPB;

    char* ws = (char*)d_ws;
    size_t off = 0;
    auto alloc = [&](size_t bytes) -> void* {
        void* p = ws + off;
        off = (off + bytes + 255) & ~(size_t)255;
        return p;
    };
    int*   deg       = (int*)alloc((size_t)N * 4);
    int*   row_start = (int*)alloc((size_t)N * 4);
    int*   bsize     = (int*)alloc((size_t)MAXBUCK * 4);
    int*   bstart    = (int*)alloc((size_t)MAXBUCK * 4);
    int*   bcursor   = (int*)alloc((size_t)MAXBUCK * 4);
    int*   bucketed  = (int*)alloc((size_t)E * 4);
    int*   sorted    = (int*)alloc((size_t)E * 4);
    float* wtab      = (float*)alloc((size_t)NLAYER * RELNUM * NHEAD * 4);
    float* h0        = (float*)alloc((size_t)N * NHEAD * 4);
    float* hs        = (float*)alloc((size_t)N * 4);
    float* hs2       = (float*)alloc((size_t)N * 4);
    _Float16* Wh     = (_Float16*)alloc((size_t)NCOL * INDIM * 2);
    _Float16* Wl     = (_Float16*)alloc((size_t)NCOL * INDIM * 2);
    (void)ws_size; (void)n_in; (void)out_size;

    (void)hipMemsetAsync(bsize, 0, (size_t)MAXBUCK * 4, stream);

    const int eb = (E + ECHUNK - 1) / ECHUNK;
    bucket_count_kernel<<<eb, 256, 0, stream>>>(dst, bsize, E, nbuck);
    scan_buckets_kernel<<<1, 1024, 0, stream>>>(bsize, bstart, bcursor, nbuck);
    bucket_scatter_kernel<<<eb, 256, 0, stream>>>(src, dst, edge_types, bcursor,
                                                  bucketed, E, nbuck);
    bucket_to_csr_kernel<<<nbuck, 256, 0, stream>>>(bstart, bsize, bucketed, sorted,
                                                    row_start, deg, N);

    table_kernel<<<(NLAYER * RELNUM * NHEAD + 255) / 256, 256, 0, stream>>>(rel_emb, W_pred, wtab);
    split_w1<<<(NCOL * INDIM) / 256, 256, 0, stream>>>(W1, Wh, Wl);
    mlp_mfma_kernel<<<(N + MLP_NODES - 1) / MLP_NODES, 256, 0, stream>>>(
        X, Wh, Wl, b1, W2, b2, h0, N);

    const int ab = (N * NHEAD + 255) / 256;
    agg_kernel<0><<<ab, 256, 0, stream>>>(row_start, deg, sorted, wtab + 0 * RELNUM * NHEAD,
                                          h0, hs, nullptr, nullptr, nullptr, N);
    agg_kernel<1><<<ab, 256, 0, stream>>>(row_start, deg, sorted, wtab + 1 * RELNUM * NHEAD,
                                          hs, hs2, nullptr, nullptr, nullptr, N);
    agg_kernel<2><<<ab, 256, 0, stream>>>(row_start, deg, sorted, wtab + 2 * RELNUM * NHEAD,
                                          hs2, out, centrality, gamma, beta, N);
}

// Round 7
// 390.469 us; speedup vs baseline: 1.0794x; 1.0794x over previous
//
#include <hip/hip_runtime.h>
#include <cstdint>
#include <cstddef>

#define NHEAD 4
#define HID 64
#define NCOL 256          // NHEAD*HID
#define INDIM 128
#define PREDDIM 16
#define RELNUM 50
#define NLAYER 3
#define ECHUNK 8192       // edges per block in bucket build
#define DSHIFT 7          // 128 dsts per bucket
#define DPB 128           // dsts per bucket
#define MAXBUCK 1024      // >= ceil(N/DPB); LDS hist size
#define MLP_NODES 64      // nodes per block in MFMA MLP

typedef _Float16 half8 __attribute__((ext_vector_type(8)));
typedef float float4v __attribute__((ext_vector_type(4)));

// ---------------- W1 hi/lo f16 split (once) ----------------
// fp32 = hi + lo/2048 exactly to ~2^-22 rel; lo scaled x2048 so W~0.05
// residuals stay in f16 normal range (avoids denorm-flush error).
__global__ void split_w1(const float* __restrict__ W1,
                         _Float16* __restrict__ Wh, _Float16* __restrict__ Wl)
{
    int i = blockIdx.x * 256 + threadIdx.x;    // NCOL*INDIM = 32768 total
    float v = W1[i];
    _Float16 h = (_Float16)v;
    Wh[i] = h;
    Wl[i] = (_Float16)((v - (float)h) * 2048.0f);
}

// ---------------- node scoring MLP via split-f16 MFMA ----------------
// Round-6 failure: every wave re-streamed all 128 KB of Wh/Wl from L2 per
// 16-node tile with 128 VGPRs of accumulators -> latency-bound, MfmaUtil 6%.
// Fix: ct-outer loop. B-frags loaded ONCE per coltile (amortized over 64
// nodes), A-frags stream from LDS, epilogue folded per mt so only 3 float4
// accumulators live. LDS-pipe-bound floor ~16 us.
// Fragment conventions (verified by round-5/6 passing): A[m=lane&15]
// [k=(lane>>4)*8+j], B[n=lane&15][k=(lane>>4)*8+j], D col=lane&15 (B n),
// row=(lane>>4)*4+reg (A m).
__global__ __launch_bounds__(256, 2) void mlp_mfma_kernel(
    const float* __restrict__ X, const _Float16* __restrict__ Wh,
    const _Float16* __restrict__ Wl, const float* __restrict__ b1,
    const float* __restrict__ W2, const float* __restrict__ b2,
    float* __restrict__ h0, int N)
{
    __shared__ _Float16 hA[4][4][64][8];   // [mt][ks][lane][j], 16 KB
    __shared__ _Float16 lA[4][4][64][8];

    const int tid = threadIdx.x;
    const int n0  = blockIdx.x * MLP_NODES;

    // ---- stage: thread = (node mg=tid>>2, ks=tid&3): 32 floats -> hi/lo ----
    {
        const int mg = tid >> 2, ks = tid & 3;
        const int gn = min(n0 + mg, N - 1);     // clamp; stores guarded later
        const float4* Xp = reinterpret_cast<const float4*>(X + (size_t)gn * INDIM + ks * 32);
        const int mt = mg >> 4, m = mg & 15;
        #pragma unroll
        for (int q = 0; q < 4; q++) {
            float4 x0 = Xp[q * 2], x1 = Xp[q * 2 + 1];
            float xs[8] = { x0.x,x0.y,x0.z,x0.w, x1.x,x1.y,x1.z,x1.w };
            half8 hv, lv;
            #pragma unroll
            for (int j = 0; j < 8; j++) {
                _Float16 hh = (_Float16)xs[j];
                hv[j] = hh;
                lv[j] = (_Float16)((xs[j] - (float)hh) * 2048.0f);
            }
            *reinterpret_cast<half8*>(&hA[mt][ks][q * 16 + m][0]) = hv;
            *reinterpret_cast<half8*>(&lA[mt][ks][q * 16 + m][0]) = lv;
        }
    }
    __syncthreads();

    const int w    = tid >> 6;             // wave = head
    const int lane = tid & 63;
    const int n16  = lane & 15;
    const int q    = lane >> 4;

    float s[4][4];                         // [mt][reg] per-head partials
    #pragma unroll
    for (int mt = 0; mt < 4; mt++)
        #pragma unroll
        for (int r = 0; r < 4; r++) s[mt][r] = 0.f;

    #pragma unroll
    for (int ct = 0; ct < 4; ct++) {
        const int c = w * 64 + ct * 16 + n16;
        const _Float16* pb = Wh + (size_t)c * INDIM + q * 8;
        const _Float16* pl = Wl + (size_t)c * INDIM + q * 8;
        half8 bh[4], bl[4];
        #pragma unroll
        for (int ks = 0; ks < 4; ks++) {
            bh[ks] = *reinterpret_cast<const half8*>(pb + ks * 32);
            bl[ks] = *reinterpret_cast<const half8*>(pl + ks * 32);
        }
        const float b1v = b1[c];
        const float w2v = W2[c];

        #pragma unroll
        for (int mt = 0; mt < 4; mt++) {
            float4v acc = (float4v){0.f,0.f,0.f,0.f};
            float4v aca = (float4v){0.f,0.f,0.f,0.f};
            float4v acb = (float4v){0.f,0.f,0.f,0.f};
            #pragma unroll
            for (int ks = 0; ks < 4; ks++) {
                half8 ah = *reinterpret_cast<const half8*>(&hA[mt][ks][lane][0]);
                half8 al = *reinterpret_cast<const half8*>(&lA[mt][ks][lane][0]);
                acc = __builtin_amdgcn_mfma_f32_16x16x32_f16(ah, bh[ks], acc, 0, 0, 0);
                aca = __builtin_amdgcn_mfma_f32_16x16x32_f16(ah, bl[ks], aca, 0, 0, 0);
                acb = __builtin_amdgcn_mfma_f32_16x16x32_f16(al, bh[ks], acb, 0, 0, 0);
            }
            #pragma unroll
            for (int r = 0; r < 4; r++) {
                float v = acc[r] + (aca[r] + acb[r]) * (1.0f / 2048.0f) + b1v;
                s[mt][r] += fmaxf(v, 0.f) * w2v;
            }
        }
    }

    // ---- reduce over n16 (16 lanes = 16 cols of this head) + store ----
    const float bk = b2[w];
    #pragma unroll
    for (int mt = 0; mt < 4; mt++) {
        #pragma unroll
        for (int r = 0; r < 4; r++) {
            float v = s[mt][r];
            v += __shfl_down(v, 8, 16);
            v += __shfl_down(v, 4, 16);
            v += __shfl_down(v, 2, 16);
            v += __shfl_down(v, 1, 16);
            if (n16 == 0) {
                int node = n0 + mt * 16 + q * 4 + r;
                if (node < N) h0[(size_t)node * NHEAD + w] = v + bk;
            }
        }
    }
}

// ---------------- attention weight table ----------------
__global__ void table_kernel(const float* __restrict__ rel_emb,
                             const float* __restrict__ W_pred,
                             float* __restrict__ wtab)
{
    int idx = blockIdx.x * blockDim.x + threadIdx.x;
    if (idx >= NLAYER * RELNUM * NHEAD) return;
    int h = idx & 3;
    int q = idx >> 2;
    int t = q % RELNUM;
    int l = q / RELNUM;
    float acc = 0.f;
    #pragma unroll
    for (int p = 0; p < PREDDIM; p++)
        acc = fmaf(rel_emb[t * PREDDIM + p], W_pred[l * PREDDIM * NHEAD + p * NHEAD + h], acc);
    float e = (acc >= 0.f) ? acc : 0.2f * acc;
    wtab[idx] = __expf(e);
}

// ---------------- bucketed CSR build ----------------
__global__ __launch_bounds__(256) void bucket_count_kernel(
    const int* __restrict__ dst, int* __restrict__ bucket_size, int E, int nbuck)
{
    __shared__ int hist[MAXBUCK];
    const int tid = threadIdx.x;
    #pragma unroll
    for (int r = 0; r < MAXBUCK / 256; r++) hist[r * 256 + tid] = 0;
    __syncthreads();
    const int base = blockIdx.x * ECHUNK;
    const int end  = min(base + ECHUNK, E);
    for (int i = base + tid; i < end; i += 256)
        atomicAdd(&hist[dst[i] >> DSHIFT], 1);
    __syncthreads();
    for (int b = tid; b < nbuck; b += 256)
        if (hist[b]) atomicAdd(&bucket_size[b], hist[b]);
}

__global__ __launch_bounds__(1024) void scan_buckets_kernel(
    const int* __restrict__ bucket_size, int* __restrict__ bucket_start,
    int* __restrict__ bucket_cursor, int nbuck)
{
    __shared__ int s[1024];
    const int t = threadIdx.x;
    int v = (t < nbuck) ? bucket_size[t] : 0;
    s[t] = v;
    __syncthreads();
    for (int off = 1; off < 1024; off <<= 1) {
        int u = (t >= off) ? s[t - off] : 0;
        __syncthreads();
        s[t] += u;
        __syncthreads();
    }
    if (t < nbuck) {
        int ex = s[t] - v;
        bucket_start[t]  = ex;
        bucket_cursor[t] = ex;
    }
}

__global__ __launch_bounds__(256) void bucket_scatter_kernel(
    const int* __restrict__ src, const int* __restrict__ dst,
    const int* __restrict__ types, int* __restrict__ bucket_cursor,
    int* __restrict__ bucketed, int E, int nbuck)
{
    __shared__ int hist[MAXBUCK];   // then per-bucket base
    __shared__ int cur[MAXBUCK];
    const int tid = threadIdx.x;
    #pragma unroll
    for (int r = 0; r < MAXBUCK / 256; r++) {
        hist[r * 256 + tid] = 0;
        cur[r * 256 + tid] = 0;
    }
    __syncthreads();
    const int base = blockIdx.x * ECHUNK;
    const int end  = min(base + ECHUNK, E);
    for (int i = base + tid; i < end; i += 256)
        atomicAdd(&hist[dst[i] >> DSHIFT], 1);
    __syncthreads();
    for (int b = tid; b < nbuck; b += 256) {
        int c = hist[b];
        if (c) hist[b] = atomicAdd(&bucket_cursor[b], c);   // reserve block's range
    }
    __syncthreads();
    for (int i = base + tid; i < end; i += 256) {
        int d = dst[i];
        int b = d >> DSHIFT;
        int r = atomicAdd(&cur[b], 1);
        bucketed[hist[b] + r] = src[i] | (types[i] << 17) | ((d & (DPB - 1)) << 23);
    }
}

__global__ __launch_bounds__(256) void bucket_to_csr_kernel(
    const int* __restrict__ bucket_start, const int* __restrict__ bucket_size,
    const int* __restrict__ bucketed, int* __restrict__ sorted,
    int* __restrict__ row_start, int* __restrict__ deg, int N)
{
    __shared__ int cnt[DPB];
    __shared__ int sc[DPB];
    __shared__ int rs[DPB];
    __shared__ int cur[DPB];
    const int tid = threadIdx.x;
    const int b   = blockIdx.x;
    const int d0  = b << DSHIFT;
    const int nd  = min(DPB, N - d0);
    const int s0  = bucket_start[b];
    const int ne  = bucket_size[b];

    if (tid < DPB) { cnt[tid] = 0; cur[tid] = 0; }
    __syncthreads();
    for (int i = tid; i < ne; i += 256)
        atomicAdd(&cnt[(bucketed[s0 + i] >> 23) & (DPB - 1)], 1);
    __syncthreads();
    int v = (tid < DPB) ? cnt[tid] : 0;
    if (tid < DPB) sc[tid] = v;
    __syncthreads();
    for (int off = 1; off < DPB; off <<= 1) {
        int u = (tid < DPB && tid >= off) ? sc[tid - off] : 0;
        __syncthreads();
        if (tid < DPB) sc[tid] += u;
        __syncthreads();
    }
    if (tid < DPB) {
        int ex = sc[tid] - v;
        rs[tid] = s0 + ex;
        if (tid < nd) {
            row_start[d0 + tid] = s0 + ex;
            deg[d0 + tid] = v;
        }
    }
    __syncthreads();
    for (int i = tid; i < ne; i += 256) {
        int pk = bucketed[s0 + i];
        int d  = (pk >> 23) & (DPB - 1);
        int r  = atomicAdd(&cur[d], 1);
        sorted[rs[d] + r] = pk & 0x7FFFFF;   // src | type<<17
    }
}

// ---------------- per-layer aggregation ----------------
template <int MODE>
__global__ __launch_bounds__(256) void agg_kernel(
    const int* __restrict__ row_start, const int* __restrict__ deg,
    const int* __restrict__ sorted, const float* __restrict__ wt_l,
    const float* __restrict__ hin, float* __restrict__ hout,
    const float* __restrict__ centrality, const float* __restrict__ gamma,
    const float* __restrict__ beta, int N)
{
    __shared__ float wt[RELNUM * NHEAD];
    for (int i = threadIdx.x; i < RELNUM * NHEAD; i += blockDim.x) wt[i] = wt_l[i];
    __syncthreads();

    int gid = blockIdx.x * blockDim.x + threadIdx.x;
    int d = gid >> 2, h = gid & 3;
    if (d >= N) return;

    int b = row_start[d], n = deg[d];
    float num = 0.f, den = 0.f;
    for (int i = 0; i < n; i++) {
        int pk = sorted[b + i];                 // same addr across the quad
        int s = pk & 0x1FFFF;
        int t = pk >> 17;
        float wv = wt[t * NHEAD + h];
        float hv = (MODE == 0) ? hin[(size_t)s * NHEAD + h] : hin[s];
        num = fmaf(wv, hv, num);
        den += wv;
    }
    float r = (n > 0) ? fmaxf(num / den, 0.f) : 0.f;   // relu(segsum(a*h))
    if (MODE == 2) r = (centrality[d] * gamma[h] + beta[h]) * r;
    r += __shfl_xor(r, 1);
    r += __shfl_xor(r, 2);
    r *= 0.25f;
    if (h == 0) {
        if (MODE < 2) hout[d] = r;
        else          hout[d] = (r > 0.f) ? r : 0.01f * r;
    }
}

// ---------------- launch ----------------
extern "C" void kernel_launch(void* const* d_in, const int* in_sizes, int n_in,
                              void* d_out, int out_size, void* d_ws, size_t ws_size,
                              hipStream_t stream)
{
    const float* X          = (const float*)d_in[0];
    const float* centrality = (const float*)d_in[1];
    const float* W1         = (const float*)d_in[2];
    const float* b1         = (const float*)d_in[3];
    const float* W2         = (const float*)d_in[4];
    const float* b2         = (const float*)d_in[5];
    const float* rel_emb    = (const float*)d_in[6];
    const float* W_pred     = (const float*)d_in[7];
    const float* gamma      = (const float*)d_in[8];
    const float* beta       = (const float*)d_in[9];
    const int*   edge_types = (const int*)d_in[10];
    const int*   src        = (const int*)d_in[11];
    const int*   dst        = (const int*)d_in[12];
    float* out = (float*)d_out;

    const int N = in_sizes[1];
    const int E = in_sizes[10];
    const int nbuck = (N + DPB - 1) / DPB;

    char* ws = (char*)d_ws;
    size_t off = 0;
    auto alloc = [&](size_t bytes) -> void* {
        void* p = ws + off;
        off = (off + bytes + 255) & ~(size_t)255;
        return p;
    };
    int*   deg       = (int*)alloc((size_t)N * 4);
    int*   row_start = (int*)alloc((size_t)N * 4);
    int*   bsize     = (int*)alloc((size_t)MAXBUCK * 4);
    int*   bstart    = (int*)alloc((size_t)MAXBUCK * 4);
    int*   bcursor   = (int*)alloc((size_t)MAXBUCK * 4);
    int*   bucketed  = (int*)alloc((size_t)E * 4);
    int*   sorted    = (int*)alloc((size_t)E * 4);
    float* wtab      = (float*)alloc((size_t)NLAYER * RELNUM * NHEAD * 4);
    float* h0        = (float*)alloc((size_t)N * NHEAD * 4);
    float* hs        = (float*)alloc((size_t)N * 4);
    float* hs2       = (float*)alloc((size_t)N * 4);
    _Float16* Wh     = (_Float16*)alloc((size_t)NCOL * INDIM * 2);
    _Float16* Wl     = (_Float16*)alloc((size_t)NCOL * INDIM * 2);
    (void)ws_size; (void)n_in; (void)out_size;

    (void)hipMemsetAsync(bsize, 0, (size_t)MAXBUCK * 4, stream);

    const int eb = (E + ECHUNK - 1) / ECHUNK;
    bucket_count_kernel<<<eb, 256, 0, stream>>>(dst, bsize, E, nbuck);
    scan_buckets_kernel<<<1, 1024, 0, stream>>>(bsize, bstart, bcursor, nbuck);
    bucket_scatter_kernel<<<eb, 256, 0, stream>>>(src, dst, edge_types, bcursor,
                                                  bucketed, E, nbuck);
    bucket_to_csr_kernel<<<nbuck, 256, 0, stream>>>(bstart, bsize, bucketed, sorted,
                                                    row_start, deg, N);

    table_kernel<<<(NLAYER * RELNUM * NHEAD + 255) / 256, 256, 0, stream>>>(rel_emb, W_pred, wtab);
    split_w1<<<(NCOL * INDIM) / 256, 256, 0, stream>>>(W1, Wh, Wl);
    mlp_mfma_kernel<<<(N + MLP_NODES - 1) / MLP_NODES, 256, 0, stream>>>(
        X, Wh, Wl, b1, W2, b2, h0, N);

    const int ab = (N * NHEAD + 255) / 256;
    agg_kernel<0><<<ab, 256, 0, stream>>>(row_start, deg, sorted, wtab + 0 * RELNUM * NHEAD,
                                          h0, hs, nullptr, nullptr, nullptr, N);
    agg_kernel<1><<<ab, 256, 0, stream>>>(row_start, deg, sorted, wtab + 1 * RELNUM * NHEAD,
                                          hs, hs2, nullptr, nullptr, nullptr, N);
    agg_kernel<2><<<ab, 256, 0, stream>>>(row_start, deg, sorted, wtab + 2 * RELNUM * NHEAD,
                                          hs2, out, centrality, gamma, beta, N);
}

// Round 8
// 343.024 us; speedup vs baseline: 1.2287x; 1.1383x over previous
//
#include <hip/hip_runtime.h>
#include <cstdint>
#include <cstddef>

#define NHEAD 4
#define HID 64
#define NCOL 256          // NHEAD*HID
#define INDIM 128
#define PREDDIM 16
#define RELNUM 50
#define NLAYER 3
#define ECHUNK 8192       // edges per block in bucket build
#define DSHIFT 7          // 128 dsts per bucket
#define DPB 128           // dsts per bucket
#define MAXBUCK 1024      // >= ceil(N/DPB); LDS hist size
#define MLP_NODES 64      // nodes per block in MFMA MLP

typedef _Float16 half8 __attribute__((ext_vector_type(8)));
typedef float float4v __attribute__((ext_vector_type(4)));

// ---------------- W1 hi/lo f16 split (once) ----------------
// fp32 = hi + lo/2048 exactly to ~2^-22 rel; lo scaled x2048 so W~0.05
// residuals stay in f16 normal range (avoids denorm-flush error).
__global__ void split_w1(const float* __restrict__ W1,
                         _Float16* __restrict__ Wh, _Float16* __restrict__ Wl)
{
    int i = blockIdx.x * 256 + threadIdx.x;    // NCOL*INDIM = 32768 total
    float v = W1[i];
    _Float16 h = (_Float16)v;
    Wh[i] = h;
    Wl[i] = (_Float16)((v - (float)h) * 2048.0f);
}

// ---------------- node scoring MLP via split-f16 MFMA ----------------
// Round-7 failure: '#pragma unroll' on the ct loop hoisted all 4 iterations'
// bh[4]/bl[4] (128 VGPRs of B-frags) -> accumulator spill -> 150 MB of
// scratch writes per dispatch (WRITE_SIZE counter), HBM-bound at 2.3 TB/s.
// Fix: ct loop NOT unrolled (unroll 1) so only one ct's B-frags (32 VGPR)
// are live; mt loop stays unrolled. Live set ~80 VGPR -> no spill.
// Fragment conventions (verified rounds 5-7 passing): A[m=lane&15]
// [k=(lane>>4)*8+j], B[n=lane&15][k=(lane>>4)*8+j], D col=lane&15 (B n),
// row=(lane>>4)*4+reg (A m).
__global__ __launch_bounds__(256, 2) void mlp_mfma_kernel(
    const float* __restrict__ X, const _Float16* __restrict__ Wh,
    const _Float16* __restrict__ Wl, const float* __restrict__ b1,
    const float* __restrict__ W2, const float* __restrict__ b2,
    float* __restrict__ h0, int N)
{
    __shared__ _Float16 hA[4][4][64][8];   // [mt][ks][lane][j], 16 KB
    __shared__ _Float16 lA[4][4][64][8];

    const int tid = threadIdx.x;
    const int n0  = blockIdx.x * MLP_NODES;

    // ---- stage: thread = (node mg=tid>>2, ks=tid&3): 32 floats -> hi/lo ----
    {
        const int mg = tid >> 2, ks = tid & 3;
        const int gn = min(n0 + mg, N - 1);     // clamp; stores guarded later
        const float4* Xp = reinterpret_cast<const float4*>(X + (size_t)gn * INDIM + ks * 32);
        const int mt = mg >> 4, m = mg & 15;
        #pragma unroll
        for (int q = 0; q < 4; q++) {
            float4 x0 = Xp[q * 2], x1 = Xp[q * 2 + 1];
            float xs[8] = { x0.x,x0.y,x0.z,x0.w, x1.x,x1.y,x1.z,x1.w };
            half8 hv, lv;
            #pragma unroll
            for (int j = 0; j < 8; j++) {
                _Float16 hh = (_Float16)xs[j];
                hv[j] = hh;
                lv[j] = (_Float16)((xs[j] - (float)hh) * 2048.0f);
            }
            *reinterpret_cast<half8*>(&hA[mt][ks][q * 16 + m][0]) = hv;
            *reinterpret_cast<half8*>(&lA[mt][ks][q * 16 + m][0]) = lv;
        }
    }
    __syncthreads();

    const int w    = tid >> 6;             // wave = head
    const int lane = tid & 63;
    const int n16  = lane & 15;
    const int q    = lane >> 4;

    float s[4][4];                         // [mt][reg] per-head partials
    #pragma unroll
    for (int mt = 0; mt < 4; mt++)
        #pragma unroll
        for (int r = 0; r < 4; r++) s[mt][r] = 0.f;

    #pragma unroll 1                       // DO NOT unroll: keeps one ct's
    for (int ct = 0; ct < 4; ct++) {       // B-frags (32 VGPR) live, not 128
        const int c = w * 64 + ct * 16 + n16;
        const _Float16* pb = Wh + (size_t)c * INDIM + q * 8;
        const _Float16* pl = Wl + (size_t)c * INDIM + q * 8;
        half8 bh[4], bl[4];
        #pragma unroll
        for (int ks = 0; ks < 4; ks++) {
            bh[ks] = *reinterpret_cast<const half8*>(pb + ks * 32);
            bl[ks] = *reinterpret_cast<const half8*>(pl + ks * 32);
        }
        const float b1v = b1[c];
        const float w2v = W2[c];

        #pragma unroll
        for (int mt = 0; mt < 4; mt++) {
            float4v acc = (float4v){0.f,0.f,0.f,0.f};
            float4v aca = (float4v){0.f,0.f,0.f,0.f};
            float4v acb = (float4v){0.f,0.f,0.f,0.f};
            #pragma unroll
            for (int ks = 0; ks < 4; ks++) {
                half8 ah = *reinterpret_cast<const half8*>(&hA[mt][ks][lane][0]);
                half8 al = *reinterpret_cast<const half8*>(&lA[mt][ks][lane][0]);
                acc = __builtin_amdgcn_mfma_f32_16x16x32_f16(ah, bh[ks], acc, 0, 0, 0);
                aca = __builtin_amdgcn_mfma_f32_16x16x32_f16(ah, bl[ks], aca, 0, 0, 0);
                acb = __builtin_amdgcn_mfma_f32_16x16x32_f16(al, bh[ks], acb, 0, 0, 0);
            }
            #pragma unroll
            for (int r = 0; r < 4; r++) {
                float v = acc[r] + (aca[r] + acb[r]) * (1.0f / 2048.0f) + b1v;
                s[mt][r] += fmaxf(v, 0.f) * w2v;
            }
        }
    }

    // ---- reduce over n16 (16 lanes = 16 cols of this head) + store ----
    const float bk = b2[w];
    #pragma unroll
    for (int mt = 0; mt < 4; mt++) {
        #pragma unroll
        for (int r = 0; r < 4; r++) {
            float v = s[mt][r];
            v += __shfl_down(v, 8, 16);
            v += __shfl_down(v, 4, 16);
            v += __shfl_down(v, 2, 16);
            v += __shfl_down(v, 1, 16);
            if (n16 == 0) {
                int node = n0 + mt * 16 + q * 4 + r;
                if (node < N) h0[(size_t)node * NHEAD + w] = v + bk;
            }
        }
    }
}

// ---------------- attention weight table ----------------
__global__ void table_kernel(const float* __restrict__ rel_emb,
                             const float* __restrict__ W_pred,
                             float* __restrict__ wtab)
{
    int idx = blockIdx.x * blockDim.x + threadIdx.x;
    if (idx >= NLAYER * RELNUM * NHEAD) return;
    int h = idx & 3;
    int q = idx >> 2;
    int t = q % RELNUM;
    int l = q / RELNUM;
    float acc = 0.f;
    #pragma unroll
    for (int p = 0; p < PREDDIM; p++)
        acc = fmaf(rel_emb[t * PREDDIM + p], W_pred[l * PREDDIM * NHEAD + p * NHEAD + h], acc);
    float e = (acc >= 0.f) ? acc : 0.2f * acc;
    wtab[idx] = __expf(e);
}

// ---------------- bucketed CSR build ----------------
__global__ __launch_bounds__(256) void bucket_count_kernel(
    const int* __restrict__ dst, int* __restrict__ bucket_size, int E, int nbuck)
{
    __shared__ int hist[MAXBUCK];
    const int tid = threadIdx.x;
    #pragma unroll
    for (int r = 0; r < MAXBUCK / 256; r++) hist[r * 256 + tid] = 0;
    __syncthreads();
    const int base = blockIdx.x * ECHUNK;
    const int end  = min(base + ECHUNK, E);
    for (int i = base + tid; i < end; i += 256)
        atomicAdd(&hist[dst[i] >> DSHIFT], 1);
    __syncthreads();
    for (int b = tid; b < nbuck; b += 256)
        if (hist[b]) atomicAdd(&bucket_size[b], hist[b]);
}

__global__ __launch_bounds__(1024) void scan_buckets_kernel(
    const int* __restrict__ bucket_size, int* __restrict__ bucket_start,
    int* __restrict__ bucket_cursor, int nbuck)
{
    __shared__ int s[1024];
    const int t = threadIdx.x;
    int v = (t < nbuck) ? bucket_size[t] : 0;
    s[t] = v;
    __syncthreads();
    for (int off = 1; off < 1024; off <<= 1) {
        int u = (t >= off) ? s[t - off] : 0;
        __syncthreads();
        s[t] += u;
        __syncthreads();
    }
    if (t < nbuck) {
        int ex = s[t] - v;
        bucket_start[t]  = ex;
        bucket_cursor[t] = ex;
    }
}

__global__ __launch_bounds__(256) void bucket_scatter_kernel(
    const int* __restrict__ src, const int* __restrict__ dst,
    const int* __restrict__ types, int* __restrict__ bucket_cursor,
    int* __restrict__ bucketed, int E, int nbuck)
{
    __shared__ int hist[MAXBUCK];   // then per-bucket base
    __shared__ int cur[MAXBUCK];
    const int tid = threadIdx.x;
    #pragma unroll
    for (int r = 0; r < MAXBUCK / 256; r++) {
        hist[r * 256 + tid] = 0;
        cur[r * 256 + tid] = 0;
    }
    __syncthreads();
    const int base = blockIdx.x * ECHUNK;
    const int end  = min(base + ECHUNK, E);
    for (int i = base + tid; i < end; i += 256)
        atomicAdd(&hist[dst[i] >> DSHIFT], 1);
    __syncthreads();
    for (int b = tid; b < nbuck; b += 256) {
        int c = hist[b];
        if (c) hist[b] = atomicAdd(&bucket_cursor[b], c);   // reserve block's range
    }
    __syncthreads();
    for (int i = base + tid; i < end; i += 256) {
        int d = dst[i];
        int b = d >> DSHIFT;
        int r = atomicAdd(&cur[b], 1);
        bucketed[hist[b] + r] = src[i] | (types[i] << 17) | ((d & (DPB - 1)) << 23);
    }
}

__global__ __launch_bounds__(256) void bucket_to_csr_kernel(
    const int* __restrict__ bucket_start, const int* __restrict__ bucket_size,
    const int* __restrict__ bucketed, int* __restrict__ sorted,
    int* __restrict__ row_start, int* __restrict__ deg, int N)
{
    __shared__ int cnt[DPB];
    __shared__ int sc[DPB];
    __shared__ int rs[DPB];
    __shared__ int cur[DPB];
    const int tid = threadIdx.x;
    const int b   = blockIdx.x;
    const int d0  = b << DSHIFT;
    const int nd  = min(DPB, N - d0);
    const int s0  = bucket_start[b];
    const int ne  = bucket_size[b];

    if (tid < DPB) { cnt[tid] = 0; cur[tid] = 0; }
    __syncthreads();
    for (int i = tid; i < ne; i += 256)
        atomicAdd(&cnt[(bucketed[s0 + i] >> 23) & (DPB - 1)], 1);
    __syncthreads();
    int v = (tid < DPB) ? cnt[tid] : 0;
    if (tid < DPB) sc[tid] = v;
    __syncthreads();
    for (int off = 1; off < DPB; off <<= 1) {
        int u = (tid < DPB && tid >= off) ? sc[tid - off] : 0;
        __syncthreads();
        if (tid < DPB) sc[tid] += u;
        __syncthreads();
    }
    if (tid < DPB) {
        int ex = sc[tid] - v;
        rs[tid] = s0 + ex;
        if (tid < nd) {
            row_start[d0 + tid] = s0 + ex;
            deg[d0 + tid] = v;
        }
    }
    __syncthreads();
    for (int i = tid; i < ne; i += 256) {
        int pk = bucketed[s0 + i];
        int d  = (pk >> 23) & (DPB - 1);
        int r  = atomicAdd(&cur[d], 1);
        sorted[rs[d] + r] = pk & 0x7FFFFF;   // src | type<<17
    }
}

// ---------------- per-layer aggregation ----------------
template <int MODE>
__global__ __launch_bounds__(256) void agg_kernel(
    const int* __restrict__ row_start, const int* __restrict__ deg,
    const int* __restrict__ sorted, const float* __restrict__ wt_l,
    const float* __restrict__ hin, float* __restrict__ hout,
    const float* __restrict__ centrality, const float* __restrict__ gamma,
    const float* __restrict__ beta, int N)
{
    __shared__ float wt[RELNUM * NHEAD];
    for (int i = threadIdx.x; i < RELNUM * NHEAD; i += blockDim.x) wt[i] = wt_l[i];
    __syncthreads();

    int gid = blockIdx.x * blockDim.x + threadIdx.x;
    int d = gid >> 2, h = gid & 3;
    if (d >= N) return;

    int b = row_start[d], n = deg[d];
    float num = 0.f, den = 0.f;
    for (int i = 0; i < n; i++) {
        int pk = sorted[b + i];                 // same addr across the quad
        int s = pk & 0x1FFFF;
        int t = pk >> 17;
        float wv = wt[t * NHEAD + h];
        float hv = (MODE == 0) ? hin[(size_t)s * NHEAD + h] : hin[s];
        num = fmaf(wv, hv, num);
        den += wv;
    }
    float r = (n > 0) ? fmaxf(num / den, 0.f) : 0.f;   // relu(segsum(a*h))
    if (MODE == 2) r = (centrality[d] * gamma[h] + beta[h]) * r;
    r += __shfl_xor(r, 1);
    r += __shfl_xor(r, 2);
    r *= 0.25f;
    if (h == 0) {
        if (MODE < 2) hout[d] = r;
        else          hout[d] = (r > 0.f) ? r : 0.01f * r;
    }
}

// ---------------- launch ----------------
extern "C" void kernel_launch(void* const* d_in, const int* in_sizes, int n_in,
                              void* d_out, int out_size, void* d_ws, size_t ws_size,
                              hipStream_t stream)
{
    const float* X          = (const float*)d_in[0];
    const float* centrality = (const float*)d_in[1];
    const float* W1         = (const float*)d_in[2];
    const float* b1         = (const float*)d_in[3];
    const float* W2         = (const float*)d_in[4];
    const float* b2         = (const float*)d_in[5];
    const float* rel_emb    = (const float*)d_in[6];
    const float* W_pred     = (const float*)d_in[7];
    const float* gamma      = (const float*)d_in[8];
    const float* beta       = (const float*)d_in[9];
    const int*   edge_types = (const int*)d_in[10];
    const int*   src        = (const int*)d_in[11];
    const int*   dst        = (const int*)d_in[12];
    float* out = (float*)d_out;

    const int N = in_sizes[1];
    const int E = in_sizes[10];
    const int nbuck = (N + DPB - 1) / DPB;

    char* ws = (char*)d_ws;
    size_t off = 0;
    auto alloc = [&](size_t bytes) -> void* {
        void* p = ws + off;
        off = (off + bytes + 255) & ~(size_t)255;
        return p;
    };
    int*   deg       = (int*)alloc((size_t)N * 4);
    int*   row_start = (int*)alloc((size_t)N * 4);
    int*   bsize     = (int*)alloc((size_t)MAXBUCK * 4);
    int*   bstart    = (int*)alloc((size_t)MAXBUCK * 4);
    int*   bcursor   = (int*)alloc((size_t)MAXBUCK * 4);
    int*   bucketed  = (int*)alloc((size_t)E * 4);
    int*   sorted    = (int*)alloc((size_t)E * 4);
    float* wtab      = (float*)alloc((size_t)NLAYER * RELNUM * NHEAD * 4);
    float* h0        = (float*)alloc((size_t)N * NHEAD * 4);
    float* hs        = (float*)alloc((size_t)N * 4);
    float* hs2       = (float*)alloc((size_t)N * 4);
    _Float16* Wh     = (_Float16*)alloc((size_t)NCOL * INDIM * 2);
    _Float16* Wl     = (_Float16*)alloc((size_t)NCOL * INDIM * 2);
    (void)ws_size; (void)n_in; (void)out_size;

    (void)hipMemsetAsync(bsize, 0, (size_t)MAXBUCK * 4, stream);

    const int eb = (E + ECHUNK - 1) / ECHUNK;
    bucket_count_kernel<<<eb, 256, 0, stream>>>(dst, bsize, E, nbuck);
    scan_buckets_kernel<<<1, 1024, 0, stream>>>(bsize, bstart, bcursor, nbuck);
    bucket_scatter_kernel<<<eb, 256, 0, stream>>>(src, dst, edge_types, bcursor,
                                                  bucketed, E, nbuck);
    bucket_to_csr_kernel<<<nbuck, 256, 0, stream>>>(bstart, bsize, bucketed, sorted,
                                                    row_start, deg, N);

    table_kernel<<<(NLAYER * RELNUM * NHEAD + 255) / 256, 256, 0, stream>>>(rel_emb, W_pred, wtab);
    split_w1<<<(NCOL * INDIM) / 256, 256, 0, stream>>>(W1, Wh, Wl);
    mlp_mfma_kernel<<<(N + MLP_NODES - 1) / MLP_NODES, 256, 0, stream>>>(
        X, Wh, Wl, b1, W2, b2, h0, N);

    const int ab = (N * NHEAD + 255) / 256;
    agg_kernel<0><<<ab, 256, 0, stream>>>(row_start, deg, sorted, wtab + 0 * RELNUM * NHEAD,
                                          h0, hs, nullptr, nullptr, nullptr, N);
    agg_kernel<1><<<ab, 256, 0, stream>>>(row_start, deg, sorted, wtab + 1 * RELNUM * NHEAD,
                                          hs, hs2, nullptr, nullptr, nullptr, N);
    agg_kernel<2><<<ab, 256, 0, stream>>>(row_start, deg, sorted, wtab + 2 * RELNUM * NHEAD,
                                          hs2, out, centrality, gamma, beta, N);
}